// Round 3
// baseline (1154.809 us; speedup 1.0000x reference)
//
#include <hip/hip_runtime.h>

// Problem constants (fixed by setup_inputs)
#define SLEN  1024
#define BATCH 32
#define EDIM  256
#define HDIM  256
#define ADIM  256

#define TT 64          // t-rows per block
#define JT 64          // j-cols per iteration
#define NTHREADS 256

#define XT_STRIDE 260  // 64 rows x 256 floats, +4 pad (16B aligned, bank rot 4)
#define P_STRIDE  68
#define W_STRIDE  20

// LDS layout (float offsets)
#define OFF_XT   0
#define OFF_XJ   (OFF_XT + TT * XT_STRIDE)        // 16640
#define OFF_P    (OFF_XJ + TT * XT_STRIDE)        // 33280 ; union { P[64][68]=4352 , Wl[256][20]=5120 }
#define OFF_DEN  (OFF_P + 5120)                   // 38400
#define OFF_SQT  (OFF_DEN + 64)
#define OFF_SQJ  (OFF_SQT + 64)
#define LDS_FLOATS (OFF_SQJ + 64)                 // 38592 floats = 154368 B

__global__ __launch_bounds__(NTHREADS, 1)
void fused_dist_attn_gate(const float* __restrict__ x, const float* __restrict__ h,
                          const float* __restrict__ wsim, const float* __restrict__ bsim,
                          const float* __restrict__ Wg, const float* __restrict__ bg,
                          float* __restrict__ out)
{
    extern __shared__ float lds[];
    float* xt  = lds + OFF_XT;   // x_t tile, later h_t tile
    float* xj  = lds + OFF_XJ;   // x_j tile -> h_j tile -> Gn tile
    float* P   = lds + OFF_P;    // P tile, later Wl
    float* Wl  = lds + OFF_P;
    float* den = lds + OFF_DEN;
    float* sqt = lds + OFF_SQT;
    float* sqj = lds + OFF_SQJ;

    const int tid = threadIdx.x;
    // XCD-bijective swizzle: all 16 t-tiles of a batch land on one XCD
    const int lin  = blockIdx.x;        // 0..511
    const int xcd  = lin & 7;
    const int kk   = lin >> 3;          // 0..63
    const int b    = (kk >> 4) * 8 + xcd;   // 0..31
    const int t0   = (kk & 15) * TT;

    const int ty = tid >> 4;   // 0..15
    const int tx = tid & 15;   // 0..15

    const float w_s = wsim[0];
    const float b_s = bsim[0];

    // G accumulators: rows {ty+16i}, col float4s at f4-index {tx+16q} (cols 4tx..4tx+3 etc.)
    float4 G[4][4];
#pragma unroll
    for (int i = 0; i < 4; ++i)
#pragma unroll
        for (int q = 0; q < 4; ++q) G[i][q] = make_float4(0.f, 0.f, 0.f, 0.f);

    if (tid < 64) den[tid] = 0.0f;

    // ---- stage x_t tile (rows t0..t0+63) ----
#pragma unroll
    for (int r = 0; r < 16; ++r) {
        int f4 = tid + NTHREADS * r;
        int row = f4 >> 6, e4 = f4 & 63;
        float4 v = *(const float4*)(x + ((size_t)(t0 + row) * BATCH + b) * EDIM + e4 * 4);
        *(float4*)(xt + row * XT_STRIDE + e4 * 4) = v;
    }
    __syncthreads();

    // ---- sqt: per-row sum of squares ----
    {
        int row = tid >> 2, sub = tid & 3;
        float s = 0.f;
#pragma unroll
        for (int k4 = 0; k4 < 16; ++k4) {
            float4 v = *(float4*)(xt + row * XT_STRIDE + sub * 64 + k4 * 4);
            s += v.x * v.x + v.y * v.y + v.z * v.z + v.w * v.w;
        }
        s += __shfl_xor(s, 1);
        s += __shfl_xor(s, 2);
        if (sub == 0) sqt[row] = s;
    }
    __syncthreads();

    // =================== j loop ===================
    for (int jt = 0; jt < SLEN / JT; ++jt) {
        const int j0 = jt * JT;

        // stage x_j tile
#pragma unroll
        for (int r = 0; r < 16; ++r) {
            int f4 = tid + NTHREADS * r;
            int row = f4 >> 6, e4 = f4 & 63;
            float4 v = *(const float4*)(x + ((size_t)(j0 + row) * BATCH + b) * EDIM + e4 * 4);
            *(float4*)(xj + row * XT_STRIDE + e4 * 4) = v;
        }
        __syncthreads();

        // sqj
        {
            int row = tid >> 2, sub = tid & 3;
            float s = 0.f;
#pragma unroll
            for (int k4 = 0; k4 < 16; ++k4) {
                float4 v = *(float4*)(xj + row * XT_STRIDE + sub * 64 + k4 * 4);
                s += v.x * v.x + v.y * v.y + v.z * v.z + v.w * v.w;
            }
            s += __shfl_xor(s, 1);
            s += __shfl_xor(s, 2);
            if (sub == 0) sqj[row] = s;
        }
        __syncthreads();

        // ---- gram: acc[i][j] = x_t[ty+16i] . x_j[tx+16j] ----
        float acc[4][4] = {};
#pragma unroll 4
        for (int kq = 0; kq < EDIM / 4; ++kq) {
            float4 a4[4], b4[4];
#pragma unroll
            for (int i = 0; i < 4; ++i) a4[i] = *(float4*)(xt + (ty + 16 * i) * XT_STRIDE + kq * 4);
#pragma unroll
            for (int j = 0; j < 4; ++j) b4[j] = *(float4*)(xj + (tx + 16 * j) * XT_STRIDE + kq * 4);
#pragma unroll
            for (int i = 0; i < 4; ++i)
#pragma unroll
                for (int j = 0; j < 4; ++j)
                    acc[i][j] += a4[i].x * b4[j].x + a4[i].y * b4[j].y +
                                 a4[i].z * b4[j].z + a4[i].w * b4[j].w;
        }

        // ---- scores -> exp -> P, row sums into den ----
        float sqjv[4];
#pragma unroll
        for (int j = 0; j < 4; ++j) sqjv[j] = sqj[tx + 16 * j];
        float rowsum[4] = {0.f, 0.f, 0.f, 0.f};
#pragma unroll
        for (int i = 0; i < 4; ++i) {
            float sqti = sqt[ty + 16 * i];
#pragma unroll
            for (int j = 0; j < 4; ++j) {
                float d2   = sqti + sqjv[j] - 2.0f * acc[i][j];
                float dist = sqrtf(fmaxf(d2, 0.0f) + 1e-12f);
                float p    = __expf(w_s * dist + b_s);   // scores bounded: no max needed
                P[(ty + 16 * i) * P_STRIDE + tx + 16 * j] = p;
                rowsum[i] += p;
            }
        }
#pragma unroll
        for (int i = 0; i < 4; ++i) {
            float s = rowsum[i];
            s += __shfl_xor(s, 1);
            s += __shfl_xor(s, 2);
            s += __shfl_xor(s, 4);
            s += __shfl_xor(s, 8);
            if (tx == 0) den[ty + 16 * i] += s;   // unique writer per row
        }
        __syncthreads();   // P/den done; xj free

        // stage h_j over xj
#pragma unroll
        for (int r = 0; r < 16; ++r) {
            int f4 = tid + NTHREADS * r;
            int row = f4 >> 6, e4 = f4 & 63;
            float4 v = *(const float4*)(h + ((size_t)(j0 + row) * BATCH + b) * HDIM + e4 * 4);
            *(float4*)(xj + row * XT_STRIDE + e4 * 4) = v;
        }
        __syncthreads();

        // ---- PV: G[rows ty+16i][f4 tx+16q] += P * h_j ----
#pragma unroll 2
        for (int jc = 0; jc < JT / 4; ++jc) {
            float4 p4[4];
#pragma unroll
            for (int i = 0; i < 4; ++i) p4[i] = *(float4*)(P + (ty + 16 * i) * P_STRIDE + jc * 4);
#pragma unroll
            for (int jj = 0; jj < 4; ++jj) {
                float4 h4[4];
#pragma unroll
                for (int q = 0; q < 4; ++q)
                    h4[q] = *(float4*)(xj + (jc * 4 + jj) * XT_STRIDE + (tx + 16 * q) * 4);
#pragma unroll
                for (int i = 0; i < 4; ++i) {
                    float pv = (jj == 0) ? p4[i].x : (jj == 1) ? p4[i].y : (jj == 2) ? p4[i].z : p4[i].w;
                    G[i][0].x += pv * h4[0].x; G[i][0].y += pv * h4[0].y;
                    G[i][0].z += pv * h4[0].z; G[i][0].w += pv * h4[0].w;
                    G[i][1].x += pv * h4[1].x; G[i][1].y += pv * h4[1].y;
                    G[i][1].z += pv * h4[1].z; G[i][1].w += pv * h4[1].w;
                    G[i][2].x += pv * h4[2].x; G[i][2].y += pv * h4[2].y;
                    G[i][2].z += pv * h4[2].z; G[i][2].w += pv * h4[2].w;
                    G[i][3].x += pv * h4[3].x; G[i][3].y += pv * h4[3].y;
                    G[i][3].z += pv * h4[3].z; G[i][3].w += pv * h4[3].w;
                }
            }
        }
        __syncthreads();   // h_j reads done before next overwrite
    }

    // =================== gate GEMM phase ===================
    // Gn = G/den -> xj buffer  (cat first half); h_t -> xt buffer (cat second half)
    {
        float inv[4];
#pragma unroll
        for (int i = 0; i < 4; ++i) inv[i] = 1.0f / den[ty + 16 * i];
#pragma unroll
        for (int i = 0; i < 4; ++i)
#pragma unroll
            for (int q = 0; q < 4; ++q) {
                float4 g = G[i][q];
                g.x *= inv[i]; g.y *= inv[i]; g.z *= inv[i]; g.w *= inv[i];
                *(float4*)(xj + (ty + 16 * i) * XT_STRIDE + (tx + 16 * q) * 4) = g;
            }
    }
#pragma unroll
    for (int r = 0; r < 16; ++r) {
        int f4 = tid + NTHREADS * r;
        int row = f4 >> 6, e4 = f4 & 63;
        float4 v = *(const float4*)(h + ((size_t)(t0 + row) * BATCH + b) * HDIM + e4 * 4);
        *(float4*)(xt + row * XT_STRIDE + e4 * 4) = v;
    }
    __syncthreads();

    // Z[rows ty+16i][a = tx+16c] over K=512 (2 halves x 16 chunks of 16)
    float Zacc[4][16] = {};
    for (int half = 0; half < 2; ++half) {
        const float* cat = (half == 0) ? xj : xt;
        for (int ch = 0; ch < 16; ++ch) {
            __syncthreads();   // previous chunk readers done
            {
                int a0 = tid >> 2, kq = tid & 3;
#pragma unroll
                for (int rr = 0; rr < 4; ++rr) {
                    int a_ = a0 + 64 * rr;
                    float4 wv = *(const float4*)(Wg + (size_t)a_ * (2 * HDIM) + half * HDIM + ch * 16 + kq * 4);
                    *(float4*)(Wl + a_ * W_STRIDE + kq * 4) = wv;
                }
            }
            __syncthreads();
#pragma unroll
            for (int kq = 0; kq < 4; ++kq) {
                float4 a4[4];
#pragma unroll
                for (int i = 0; i < 4; ++i)
                    a4[i] = *(const float4*)(cat + (ty + 16 * i) * XT_STRIDE + ch * 16 + kq * 4);
#pragma unroll
                for (int c = 0; c < 16; ++c) {
                    float4 w4 = *(float4*)(Wl + (tx + 16 * c) * W_STRIDE + kq * 4);
#pragma unroll
                    for (int i = 0; i < 4; ++i)
                        Zacc[i][c] += a4[i].x * w4.x + a4[i].y * w4.y +
                                      a4[i].z * w4.z + a4[i].w * w4.w;
                }
            }
        }
    }

    // epilogue: bias + tanh + store
#pragma unroll
    for (int c = 0; c < 16; ++c) {
        int a_ = tx + 16 * c;
        float bgv = bg[a_];
#pragma unroll
        for (int i = 0; i < 4; ++i) {
            int row = t0 + ty + 16 * i;
            out[((size_t)row * BATCH + b) * ADIM + a_] = tanhf(Zacc[i][c] + bgv);
        }
    }
}

extern "C" void kernel_launch(void* const* d_in, const int* in_sizes, int n_in,
                              void* d_out, int out_size, void* d_ws, size_t ws_size,
                              hipStream_t stream) {
    const float* x    = (const float*)d_in[0];
    const float* h    = (const float*)d_in[1];
    const float* wsim = (const float*)d_in[2];
    const float* bsim = (const float*)d_in[3];
    const float* Wg   = (const float*)d_in[4];
    const float* bg   = (const float*)d_in[5];
    float* out = (float*)d_out;

    const size_t shmem = (size_t)LDS_FLOATS * sizeof(float);   // ~151 KB
    (void)hipFuncSetAttribute((const void*)fused_dist_attn_gate,
                              hipFuncAttributeMaxDynamicSharedMemorySize, (int)shmem);
    hipLaunchKernelGGL(fused_dist_attn_gate, dim3(512), dim3(NTHREADS), shmem, stream,
                       x, h, wsim, bsim, Wg, bg, out);
}

// Round 6
// 275.573 us; speedup vs baseline: 4.1906x; 4.1906x over previous
//
#include <hip/hip_runtime.h>

// S=1024 B=32 E=H=A=256, all f32 in/out.
// Fully fused: gram(bf16 MFMA) -> exp -> PV(bf16 MFMA) -> normalize -> gate(split-bf16 3-pass MFMA) -> tanh
#define SLEN  1024
#define BATCH 32
#define EDIM  256
#define HDIM  256
#define ADIM  256
#define NTH   256

typedef __attribute__((ext_vector_type(8))) short short8;
typedef __attribute__((ext_vector_type(4))) float f32x4;
typedef __attribute__((ext_vector_type(4))) unsigned int u32x4;

#define XJ_STRIDE 264            // bf16 units per row (256 + 8 pad -> 132 words: bank rot 4, even 8/bank for frag reads)
#define P_STRIDE  72             // bf16 units (64 + 8 pad -> 36 words: bank rot 4)

#define OFF_XJ  0                // ushort [64][264] = 33792 B  (x_t stage -> x_j per tile -> cat_hi in gate)
#define OFF_HT  33792            // h^T swizzled 32768 B (-> cat_lo [64][264] in gate, spills into P region)
#define OFF_P   66560            // ushort [64][72] = 9216 B
#define OFF_SQT 75776            // float[64]
#define OFF_SQJ 76032            // float[64]
#define LDS_BYTES 76288          // 2 blocks/CU (152.6 KB < 160 KB)

static __device__ __forceinline__ unsigned short f2bf(float f) {
    unsigned int u = __float_as_uint(f);
    u += 0x7FFFu + ((u >> 16) & 1u);            // RNE
    return (unsigned short)(u >> 16);
}
static __device__ __forceinline__ float bf2f(unsigned short s) {
    return __uint_as_float(((unsigned int)s) << 16);
}

// stage 64 rows x 256 f32 -> bf16 tile [64][XJ_STRIDE], per-row sum-of-squares of the bf16 values
static __device__ __forceinline__ void stage64(const float* __restrict__ src, int row0, int b,
                                               unsigned short* dst, float* sqout, int tid)
{
#pragma unroll
    for (int r = 0; r < 8; ++r) {
        int idx = tid + NTH * r;                 // 0..2047 = 64 rows x 32 chunks
        int row = idx >> 5;
        int e8  = idx & 31;
        const float* p = src + ((size_t)(row0 + row) * BATCH + b) * EDIM + e8 * 8;
        float4 v0 = *(const float4*)p;
        float4 v1 = *(const float4*)(p + 4);
        float vv[8] = {v0.x, v0.y, v0.z, v0.w, v1.x, v1.y, v1.z, v1.w};
        short8 pk;
        float s = 0.f;
#pragma unroll
        for (int e = 0; e < 8; ++e) {
            unsigned short us = f2bf(vv[e]);
            pk[e] = (short)us;
            float hf = bf2f(us);
            s += hf * hf;
        }
        *(short8*)(dst + row * XJ_STRIDE + e8 * 8) = pk;   // ds_write_b128, even banks
        s += __shfl_xor(s, 1);
        s += __shfl_xor(s, 2);
        s += __shfl_xor(s, 4);
        s += __shfl_xor(s, 8);
        s += __shfl_xor(s, 16);
        if ((tid & 31) == 0) sqout[row] = s;
    }
}

// stage 64 rows x 256 f32 -> split bf16 hi/lo tiles (for gate A-operand)
static __device__ __forceinline__ void stage64_split(const float* __restrict__ src, int row0, int b,
                                                     unsigned short* dhi, unsigned short* dlo, int tid)
{
#pragma unroll
    for (int r = 0; r < 8; ++r) {
        int idx = tid + NTH * r;
        int row = idx >> 5;
        int e8  = idx & 31;
        const float* p = src + ((size_t)(row0 + row) * BATCH + b) * HDIM + e8 * 8;
        float4 v0 = *(const float4*)p;
        float4 v1 = *(const float4*)(p + 4);
        float vv[8] = {v0.x, v0.y, v0.z, v0.w, v1.x, v1.y, v1.z, v1.w};
        short8 ph, plo;
#pragma unroll
        for (int e = 0; e < 8; ++e) {
            unsigned short hi = f2bf(vv[e]);
            ph[e] = (short)hi;
            plo[e] = (short)f2bf(vv[e] - bf2f(hi));
        }
        *(short8*)(dhi + row * XJ_STRIDE + e8 * 8) = ph;
        *(short8*)(dlo + row * XJ_STRIDE + e8 * 8) = plo;
    }
}

__global__ __launch_bounds__(NTH, 2)
void fused_mfma(const float* __restrict__ x, const float* __restrict__ h,
                const float* __restrict__ wsim, const float* __restrict__ bsim,
                const float* __restrict__ Wg, const float* __restrict__ bg,
                float* __restrict__ out)
{
    extern __shared__ char smem[];
    unsigned short* xjb    = (unsigned short*)(smem + OFF_XJ);
    char*           htb    = smem + OFF_HT;
    unsigned short* Pl     = (unsigned short*)(smem + OFF_P);
    float*          sqt_l  = (float*)(smem + OFF_SQT);
    float*          sqj_l  = (float*)(smem + OFF_SQJ);
    unsigned short* cat_hi = xjb;                              // gate-phase reuse
    unsigned short* cat_lo = (unsigned short*)(smem + OFF_HT);

    const int tid  = threadIdx.x;
    const int lane = tid & 63;
    const int w    = tid >> 6;    // wave 0..3 ; owns t-rows [16w,16w+16)
    const int lr   = lane & 15;   // A-row / B-col / C-col lane index
    const int lg   = lane >> 4;   // k-group / C-row group

    // XCD-bijective swizzle: 16 t-tiles of one batch land on one XCD
    const int lin = blockIdx.x;
    const int xcd = lin & 7;
    const int kk  = lin >> 3;
    const int b   = (kk >> 4) * 8 + xcd;
    const int t0  = (kk & 15) * 64;

    const float w_s = wsim[0];
    const float b_s = bsim[0];

    // ---- hoist x_t as A-fragments (stage via xjb, then read frags) ----
    stage64(x, t0, b, xjb, sqt_l, tid);
    __syncthreads();
    short8 at[8];
#pragma unroll
    for (int kc = 0; kc < 8; ++kc)
        at[kc] = *(short8*)(xjb + (16 * w + lr) * XJ_STRIDE + kc * 32 + lg * 8);
    float sqt_reg[4];
#pragma unroll
    for (int g2 = 0; g2 < 4; ++g2) sqt_reg[g2] = sqt_l[16 * w + 4 * lg + g2];
    __syncthreads();

    float rsum[4] = {0.f, 0.f, 0.f, 0.f};   // per-row exp-sum partials (rows 16w+4lg+reg)
    f32x4 Gacc[16];
#pragma unroll
    for (int n = 0; n < 16; ++n) Gacc[n] = (f32x4){0.f, 0.f, 0.f, 0.f};

    const size_t jstride = (size_t)BATCH * HDIM;

    // =================== j-tile loop ===================
    for (int jt = 0; jt < 16; ++jt) {
        const int j0 = jt * 64;
        stage64(x, j0, b, xjb, sqj_l, tid);
        // h^T stage: thread = column c=tid, 8 j-quads; XOR-quad swizzle keeps both write & read even
        {
            const float* hp = h + (size_t)j0 * jstride + (size_t)b * HDIM + tid;
#pragma unroll
            for (int q = 0; q < 8; ++q) {
                const float* pq = hp + (size_t)(8 * q) * jstride;
                unsigned int d0 = (unsigned int)f2bf(pq[0])           | ((unsigned int)f2bf(pq[jstride]) << 16);
                unsigned int d1 = (unsigned int)f2bf(pq[2 * jstride]) | ((unsigned int)f2bf(pq[3 * jstride]) << 16);
                unsigned int d2 = (unsigned int)f2bf(pq[4 * jstride]) | ((unsigned int)f2bf(pq[5 * jstride]) << 16);
                unsigned int d3 = (unsigned int)f2bf(pq[6 * jstride]) | ((unsigned int)f2bf(pq[7 * jstride]) << 16);
                *(u32x4*)(htb + tid * 128 + 16 * (q ^ (tid & 7))) = (u32x4){d0, d1, d2, d3};
            }
        }
        __syncthreads();

        // ---- gram: scores tile (16 t x 64 j) per wave, A=x_t(regs), B=x_j(LDS) ----
        f32x4 acc[4];
#pragma unroll
        for (int n = 0; n < 4; ++n) {
            acc[n] = (f32x4){0.f, 0.f, 0.f, 0.f};
#pragma unroll
            for (int kc = 0; kc < 8; ++kc) {
                short8 bf = *(short8*)(xjb + (16 * n + lr) * XJ_STRIDE + kc * 32 + lg * 8);
                acc[n] = __builtin_amdgcn_mfma_f32_16x16x32_bf16(at[kc], bf, acc[n], 0, 0, 0);
            }
        }

        // ---- dist -> exp -> P(bf16 LDS), accumulate row sums in regs ----
        float sqjv[4];
#pragma unroll
        for (int n = 0; n < 4; ++n) sqjv[n] = sqj_l[16 * n + lr];
#pragma unroll
        for (int n = 0; n < 4; ++n) {
#pragma unroll
            for (int g2 = 0; g2 < 4; ++g2) {
                float d2v  = sqt_reg[g2] + sqjv[n] - 2.0f * acc[n][g2];
                float dist = sqrtf(fmaxf(d2v, 0.0f) + 1e-12f);
                float pv   = __expf(fmaf(w_s, dist, b_s));   // bounded scores: no max-subtract needed
                rsum[g2] += pv;
                Pl[(16 * w + 4 * lg + g2) * P_STRIDE + 16 * n + lr] = f2bf(pv);
            }
        }

        // ---- PV: Gacc += P(16t x 64j) * h(64j x 256c); A=P rows owned by this wave ----
        short8 pa0 = *(short8*)(Pl + (16 * w + lr) * P_STRIDE + lg * 8);
        short8 pa1 = *(short8*)(Pl + (16 * w + lr) * P_STRIDE + 32 + lg * 8);
#pragma unroll
        for (int n = 0; n < 16; ++n) {
            int c = 16 * n + lr;
            short8 b0 = *(short8*)(htb + c * 128 + 16 * (lg ^ (c & 7)));
            short8 b1 = *(short8*)(htb + c * 128 + 16 * ((4 + lg) ^ (c & 7)));
            Gacc[n] = __builtin_amdgcn_mfma_f32_16x16x32_bf16(pa0, b0, Gacc[n], 0, 0, 0);
            Gacc[n] = __builtin_amdgcn_mfma_f32_16x16x32_bf16(pa1, b1, Gacc[n], 0, 0, 0);
        }
        __syncthreads();   // all reads done before next staging
    }

    // ---- finalize denominators (register-only; each wave owns its rows) ----
    float inv[4];
#pragma unroll
    for (int g2 = 0; g2 < 4; ++g2) {
        float s = rsum[g2];
        s += __shfl_xor(s, 1);
        s += __shfl_xor(s, 2);
        s += __shfl_xor(s, 4);
        s += __shfl_xor(s, 8);
        inv[g2] = 1.0f / s;
    }

    // ---- stage Gn as split-bf16 cat tiles (K = 0..255 of concat) ----
#pragma unroll
    for (int n = 0; n < 16; ++n) {
#pragma unroll
        for (int g2 = 0; g2 < 4; ++g2) {
            float gn = Gacc[n][g2] * inv[g2];
            unsigned short hi = f2bf(gn);
            unsigned short lo = f2bf(gn - bf2f(hi));
            int t = 16 * w + 4 * lg + g2;
            int c = 16 * n + lr;
            cat_hi[t * XJ_STRIDE + c] = hi;
            cat_lo[t * XJ_STRIDE + c] = lo;
        }
    }
    __syncthreads();

    // ---- gate GEMM: Z = cat(64t x 512k) * Wg^T, split-bf16 3-pass; wave owns a-cols [64w,64w+64) ----
    f32x4 Z[4][4];
#pragma unroll
    for (int m = 0; m < 4; ++m)
#pragma unroll
        for (int n = 0; n < 4; ++n) Z[m][n] = (f32x4){0.f, 0.f, 0.f, 0.f};

    for (int half = 0; half < 2; ++half) {
        if (half == 1) {
            __syncthreads();
            stage64_split(h, t0, b, cat_hi, cat_lo, tid);   // second half of concat = h_t
            __syncthreads();
        }
#pragma unroll
        for (int kc = 0; kc < 8; ++kc) {
            short8 ah[4], al[4];
#pragma unroll
            for (int m = 0; m < 4; ++m) {
                ah[m] = *(short8*)(cat_hi + (16 * m + lr) * XJ_STRIDE + kc * 32 + lg * 8);
                al[m] = *(short8*)(cat_lo + (16 * m + lr) * XJ_STRIDE + kc * 32 + lg * 8);
            }
#pragma unroll
            for (int n = 0; n < 4; ++n) {
                int a_ = 64 * w + 16 * n + lr;
                const float* wp = Wg + (size_t)a_ * (2 * HDIM) + half * HDIM + kc * 32 + lg * 8;
                float4 wv0 = *(const float4*)wp;
                float4 wv1 = *(const float4*)(wp + 4);
                float vv[8] = {wv0.x, wv0.y, wv0.z, wv0.w, wv1.x, wv1.y, wv1.z, wv1.w};
                short8 bh, bl;
#pragma unroll
                for (int e = 0; e < 8; ++e) {
                    unsigned short hi = f2bf(vv[e]);
                    bh[e] = (short)hi;
                    bl[e] = (short)f2bf(vv[e] - bf2f(hi));
                }
#pragma unroll
                for (int m = 0; m < 4; ++m) {
                    Z[m][n] = __builtin_amdgcn_mfma_f32_16x16x32_bf16(ah[m], bh, Z[m][n], 0, 0, 0);
                    Z[m][n] = __builtin_amdgcn_mfma_f32_16x16x32_bf16(al[m], bh, Z[m][n], 0, 0, 0);
                    Z[m][n] = __builtin_amdgcn_mfma_f32_16x16x32_bf16(ah[m], bl, Z[m][n], 0, 0, 0);
                }
            }
        }
    }

    // ---- epilogue: bias + tanh + store ----
#pragma unroll
    for (int n = 0; n < 4; ++n) {
        int a_ = 64 * w + 16 * n + lr;
        float bgv = bg[a_];
#pragma unroll
        for (int m = 0; m < 4; ++m) {
#pragma unroll
            for (int g2 = 0; g2 < 4; ++g2) {
                int t = 16 * m + 4 * lg + g2;
                float z  = Z[m][n][g2] + bgv;
                float e2 = __expf(2.0f * z);
                float tz = 1.0f - 2.0f / (e2 + 1.0f);
                out[((size_t)(t0 + t) * BATCH + b) * ADIM + a_] = tz;
            }
        }
    }
}

extern "C" void kernel_launch(void* const* d_in, const int* in_sizes, int n_in,
                              void* d_out, int out_size, void* d_ws, size_t ws_size,
                              hipStream_t stream) {
    const float* x    = (const float*)d_in[0];
    const float* h    = (const float*)d_in[1];
    const float* wsim = (const float*)d_in[2];
    const float* bsim = (const float*)d_in[3];
    const float* Wg   = (const float*)d_in[4];
    const float* bg   = (const float*)d_in[5];
    float* out = (float*)d_out;

    (void)hipFuncSetAttribute((const void*)fused_mfma,
                              hipFuncAttributeMaxDynamicSharedMemorySize, LDS_BYTES);
    hipLaunchKernelGGL(fused_mfma, dim3(512), dim3(NTH), LDS_BYTES, stream,
                       x, h, wsim, bsim, Wg, bg, out);
}

// Round 7
// 226.721 us; speedup vs baseline: 5.0935x; 1.2155x over previous
//
#include <hip/hip_runtime.h>

// S=1024 B=32 E=H=A=256, f32 in/out.
// Two-phase: prepass converts x/h/Wg to bf16 (+hi/lo split, +h^T, +row norms) into d_ws;
// main kernel stages via global_load_lds from pre-swizzled layouts (zero staging VALU).
// Falls back to the validated single-kernel path if ws_size is too small.
#define SLEN  1024
#define BATCH 32
#define EDIM  256
#define HDIM  256
#define ADIM  256
#define NTH   256

typedef __attribute__((ext_vector_type(8))) short short8;
typedef __attribute__((ext_vector_type(4))) float f32x4;
typedef __attribute__((ext_vector_type(4))) unsigned int u32x4;
typedef __attribute__((ext_vector_type(4))) unsigned short ushort4v;

// ---- workspace layout (bytes) ----
#define XBF_OFF  0u            // bf16 x  [b][j][256], 16B-chunk slot = chunk ^ (j&7)
#define HT_OFF   16777216u     // bf16 h^T [b][c][1024], per-8-chunk-group slot = q ^ (c&7)
#define HHI_OFF  33554432u     // bf16 hi(h) [b][j][256], slot = chunk ^ (j&7)
#define HLO_OFF  50331648u     // bf16 lo(h) same layout
#define WGHI_OFF 67108864u     // bf16 hi(Wg) [a][512] linear
#define WGLO_OFF 67371008u     // bf16 lo(Wg) linear
#define SQX_OFF  67633152u     // f32 sq-norms [b][j]
#define WS_NEED  67764224u

static __device__ __forceinline__ unsigned short f2bf(float f) {
    unsigned int u = __float_as_uint(f);
    u += 0x7FFFu + ((u >> 16) & 1u);            // RNE
    return (unsigned short)(u >> 16);
}
static __device__ __forceinline__ float bf2f(unsigned short s) {
    return __uint_as_float(((unsigned int)s) << 16);
}
static __device__ __forceinline__ void gload16(const void* g, void* l) {
    __builtin_amdgcn_global_load_lds(
        (const __attribute__((address_space(1))) unsigned int*)g,
        (__attribute__((address_space(3))) unsigned int*)l, 16, 0, 0);
}

// ================= prepass: x -> xbf(+sq), h -> hhi/hlo =================
__global__ __launch_bounds__(NTH)
void pre_convert(const float* __restrict__ x, const float* __restrict__ h,
                 unsigned short* __restrict__ xbf, unsigned short* __restrict__ hhi,
                 unsigned short* __restrict__ hlo, float* __restrict__ sqx)
{
    const int blk = blockIdx.x, tid = threadIdx.x;
    const int isx = (blk < 4096);
    const int rblk = isx ? blk : blk - 4096;
    const int row = rblk * 8 + (tid >> 5);      // row = j*32 + b
    const int j = row >> 5, b = row & 31;
    const int chunk = tid & 31;
    const float* p = (isx ? x : h) + (size_t)row * 256 + chunk * 8;
    float4 v0 = *(const float4*)p, v1 = *(const float4*)(p + 4);
    float vv[8] = {v0.x, v0.y, v0.z, v0.w, v1.x, v1.y, v1.z, v1.w};
    short8 hi8;
    float lof[8];
    float s = 0.f;
#pragma unroll
    for (int e = 0; e < 8; ++e) {
        unsigned short us = f2bf(vv[e]);
        hi8[e] = (short)us;
        float hf = bf2f(us);
        s += hf * hf;
        lof[e] = vv[e] - hf;
    }
    const size_t dst = ((size_t)b * 1024 + j) * 256 + (size_t)((chunk ^ (j & 7)) * 8);
    if (isx) {
        *(short8*)(xbf + dst) = hi8;
        s += __shfl_xor(s, 1);
        s += __shfl_xor(s, 2);
        s += __shfl_xor(s, 4);
        s += __shfl_xor(s, 8);
        s += __shfl_xor(s, 16);
        if ((tid & 31) == 0) sqx[b * 1024 + j] = s;
    } else {
        *(short8*)(hhi + dst) = hi8;
        short8 lo8;
#pragma unroll
        for (int e = 0; e < 8; ++e) lo8[e] = (short)f2bf(lof[e]);
        *(short8*)(hlo + dst) = lo8;
    }
}

// ================= prepass: h -> h^T bf16 (swizzled groups) =================
__global__ __launch_bounds__(NTH)
void pre_ht(const float* __restrict__ h, unsigned short* __restrict__ hT)
{
    __shared__ unsigned short tl[64][72];
    const int blk = blockIdx.x, tid = threadIdx.x;
    const int b = blk & 31, jt = (blk >> 5) & 15, ct = blk >> 9;
    const int jj0 = tid >> 4, cq = tid & 15;
#pragma unroll
    for (int it = 0; it < 4; ++it) {
        int jj = jj0 + it * 16;
        const float* p = h + ((size_t)(jt * 64 + jj) * BATCH + b) * HDIM + ct * 64 + cq * 4;
        float4 v = *(const float4*)p;
        ushort4v u;
        u.x = f2bf(v.x); u.y = f2bf(v.y); u.z = f2bf(v.z); u.w = f2bf(v.w);
        *(ushort4v*)&tl[jj][cq * 4] = u;
    }
    __syncthreads();
#pragma unroll
    for (int it = 0; it < 2; ++it) {
        int idx = tid + it * 256;
        int cc = idx >> 3, slot = idx & 7;
        int chunk = slot ^ (cc & 7);
        short8 o;
#pragma unroll
        for (int e = 0; e < 8; ++e) o[e] = (short)tl[chunk * 8 + e][cc];
        *(short8*)(hT + ((size_t)b * 256 + ct * 64 + cc) * 1024 + jt * 64 + slot * 8) = o;
    }
}

// ================= prepass: Wg -> hi/lo bf16 =================
__global__ __launch_bounds__(NTH)
void pre_wg(const float* __restrict__ Wg, unsigned short* __restrict__ wghi,
            unsigned short* __restrict__ wglo)
{
    const int id = blockIdx.x * NTH + threadIdx.x;   // 16384 chunks of 8
    const float* p = Wg + (size_t)id * 8;
    float4 v0 = *(const float4*)p, v1 = *(const float4*)(p + 4);
    float vv[8] = {v0.x, v0.y, v0.z, v0.w, v1.x, v1.y, v1.z, v1.w};
    short8 hi8, lo8;
#pragma unroll
    for (int e = 0; e < 8; ++e) {
        unsigned short hi = f2bf(vv[e]);
        hi8[e] = (short)hi;
        lo8[e] = (short)f2bf(vv[e] - bf2f(hi));
    }
    *(short8*)(wghi + (size_t)id * 8) = hi8;
    *(short8*)(wglo + (size_t)id * 8) = lo8;
}

// ================= main fused kernel (phase 2) =================
// LDS: XJ 32KB (x_j tile / cat_hi) | HT 32KB (h^T tile / cat_lo) | P [64][72] ushort
#define L_XJ 0
#define L_HT 32768
#define L_P  65536
#define LDS2_BYTES 74752

__global__ __launch_bounds__(NTH, 2)
void fused2(const unsigned short* __restrict__ xbf, const unsigned short* __restrict__ hT,
            const unsigned short* __restrict__ hhi, const unsigned short* __restrict__ hlo,
            const unsigned short* __restrict__ wghi, const unsigned short* __restrict__ wglo,
            const float* __restrict__ sqx, const float* __restrict__ wsim,
            const float* __restrict__ bsim, const float* __restrict__ bg,
            float* __restrict__ out)
{
    extern __shared__ char smem[];
    char* XJ = smem + L_XJ;
    char* HT = smem + L_HT;
    unsigned short* Pl = (unsigned short*)(smem + L_P);

    const int tid  = threadIdx.x;
    const int lane = tid & 63;
    const int w    = tid >> 6;
    const int lr   = lane & 15;
    const int lg   = lane >> 4;
    const int key  = lr & 7;

    const int lin = blockIdx.x;
    const int xcd = lin & 7;
    const int kk  = lin >> 3;
    const int b   = (kk >> 4) * 8 + xcd;
    const int t0  = (kk & 15) * 64;

    const float w_s = wsim[0];
    const float b_s = bsim[0];

    // A-frags of x_t direct from pre-swizzled global (L2/L3-resident)
    short8 at[8];
    {
        const unsigned short* rp = xbf + ((size_t)b * 1024 + t0 + 16 * w + lr) * 256;
#pragma unroll
        for (int kc = 0; kc < 8; ++kc)
            at[kc] = *(const short8*)(rp + (((kc * 4 + lg) ^ key) << 3));
    }
    float sqt_reg[4];
#pragma unroll
    for (int g2 = 0; g2 < 4; ++g2) sqt_reg[g2] = sqx[b * 1024 + t0 + 16 * w + 4 * lg + g2];

    float rsum[4] = {0.f, 0.f, 0.f, 0.f};
    f32x4 Gacc[16];
#pragma unroll
    for (int n = 0; n < 16; ++n) Gacc[n] = (f32x4){0.f, 0.f, 0.f, 0.f};

    for (int jt = 0; jt < 16; ++jt) {
        const int j0 = jt * 64;
        // stage x_j: wave w rows [16w,16w+16), contiguous 8KB, linear LDS dest
        {
            const char* sx = (const char*)(xbf + ((size_t)b * 1024 + j0 + 16 * w) * 256);
            char* dx = XJ + 16 * w * 512;
#pragma unroll
            for (int i = 0; i < 8; ++i)
                gload16(sx + i * 1024 + lane * 16, dx + i * 1024);
        }
        // stage h^T: wave w c-rows [64w,64w+64), group jt (128B/row), per-lane src
        {
#pragma unroll
            for (int i = 0; i < 8; ++i) {
                const char* sh = (const char*)(hT + ((size_t)b * 256 + 64 * w + i * 8 + (lane >> 3)) * 1024)
                                 + jt * 128 + (lane & 7) * 16;
                gload16(sh, HT + w * 8192 + i * 1024);
            }
        }
        float sqjv[4];
#pragma unroll
        for (int n = 0; n < 4; ++n) sqjv[n] = sqx[b * 1024 + j0 + 16 * n + lr];
        __syncthreads();

        // gram
        f32x4 acc[4];
#pragma unroll
        for (int n = 0; n < 4; ++n) {
            acc[n] = (f32x4){0.f, 0.f, 0.f, 0.f};
#pragma unroll
            for (int kc = 0; kc < 8; ++kc) {
                short8 bf = *(const short8*)(XJ + (16 * n + lr) * 512 + (((kc * 4 + lg) ^ key) << 4));
                acc[n] = __builtin_amdgcn_mfma_f32_16x16x32_bf16(at[kc], bf, acc[n], 0, 0, 0);
            }
        }

        // dist -> exp -> P
#pragma unroll
        for (int n = 0; n < 4; ++n) {
#pragma unroll
            for (int g2 = 0; g2 < 4; ++g2) {
                float d2v  = sqt_reg[g2] + sqjv[n] - 2.0f * acc[n][g2];
                float dist = sqrtf(fmaxf(d2v, 0.0f) + 1e-12f);
                float pv   = __expf(fmaf(w_s, dist, b_s));
                rsum[g2] += pv;
                Pl[(16 * w + 4 * lg + g2) * 72 + 16 * n + lr] = f2bf(pv);
            }
        }

        // PV (P rows wave-private; no barrier needed between write and read)
        short8 pa0 = *(const short8*)(Pl + (16 * w + lr) * 72 + lg * 8);
        short8 pa1 = *(const short8*)(Pl + (16 * w + lr) * 72 + 32 + lg * 8);
#pragma unroll
        for (int n = 0; n < 16; ++n) {
            const char* hrow = HT + (16 * n + lr) * 128;
            short8 b0 = *(const short8*)(hrow + ((lg ^ key) << 4));
            short8 b1 = *(const short8*)(hrow + (((4 + lg) ^ key) << 4));
            Gacc[n] = __builtin_amdgcn_mfma_f32_16x16x32_bf16(pa0, b0, Gacc[n], 0, 0, 0);
            Gacc[n] = __builtin_amdgcn_mfma_f32_16x16x32_bf16(pa1, b1, Gacc[n], 0, 0, 0);
        }
        __syncthreads();
    }

    // denominators (register-only)
    float inv[4];
#pragma unroll
    for (int g2 = 0; g2 < 4; ++g2) {
        float s = rsum[g2];
        s += __shfl_xor(s, 1);
        s += __shfl_xor(s, 2);
        s += __shfl_xor(s, 4);
        s += __shfl_xor(s, 8);
        inv[g2] = 1.0f / s;
    }

    // Gn -> cat_hi/cat_lo (swizzled, slot = chunk ^ (t&7))
#pragma unroll
    for (int n = 0; n < 16; ++n) {
#pragma unroll
        for (int g2 = 0; g2 < 4; ++g2) {
            int t = 16 * w + 4 * lg + g2;
            int c = 16 * n + lr;
            float gn = Gacc[n][g2] * inv[g2];
            unsigned short hi = f2bf(gn);
            unsigned short lo = f2bf(gn - bf2f(hi));
            int off = t * 512 + (((c >> 3) ^ (t & 7)) << 4) + ((c & 7) << 1);
            *(unsigned short*)(XJ + off) = hi;
            *(unsigned short*)(HT + off) = lo;
        }
    }
    __syncthreads();

    // gate GEMM: 3-pass split-bf16
    f32x4 Z[4][4];
#pragma unroll
    for (int m = 0; m < 4; ++m)
#pragma unroll
        for (int n = 0; n < 4; ++n) Z[m][n] = (f32x4){0.f, 0.f, 0.f, 0.f};

    for (int half = 0; half < 2; ++half) {
        if (half == 1) {
            __syncthreads();
            const char* shi = (const char*)(hhi + ((size_t)b * 1024 + t0 + 16 * w) * 256);
            const char* slo = (const char*)(hlo + ((size_t)b * 1024 + t0 + 16 * w) * 256);
#pragma unroll
            for (int i = 0; i < 8; ++i)
                gload16(shi + i * 1024 + lane * 16, XJ + 16 * w * 512 + i * 1024);
#pragma unroll
            for (int i = 0; i < 8; ++i)
                gload16(slo + i * 1024 + lane * 16, HT + 16 * w * 512 + i * 1024);
            __syncthreads();
        }
#pragma unroll
        for (int kc = 0; kc < 8; ++kc) {
            short8 ah[4], al[4];
#pragma unroll
            for (int m = 0; m < 4; ++m) {
                int off = (16 * m + lr) * 512 + (((kc * 4 + lg) ^ key) << 4);
                ah[m] = *(const short8*)(XJ + off);
                al[m] = *(const short8*)(HT + off);
            }
#pragma unroll
            for (int n = 0; n < 4; ++n) {
                int a_ = 64 * w + 16 * n + lr;
                short8 bh = *(const short8*)(wghi + (size_t)a_ * 512 + half * 256 + kc * 32 + lg * 8);
                short8 bl = *(const short8*)(wglo + (size_t)a_ * 512 + half * 256 + kc * 32 + lg * 8);
#pragma unroll
                for (int m = 0; m < 4; ++m) {
                    Z[m][n] = __builtin_amdgcn_mfma_f32_16x16x32_bf16(ah[m], bh, Z[m][n], 0, 0, 0);
                    Z[m][n] = __builtin_amdgcn_mfma_f32_16x16x32_bf16(al[m], bh, Z[m][n], 0, 0, 0);
                    Z[m][n] = __builtin_amdgcn_mfma_f32_16x16x32_bf16(ah[m], bl, Z[m][n], 0, 0, 0);
                }
            }
        }
    }

    // epilogue
#pragma unroll
    for (int n = 0; n < 4; ++n) {
        int a_ = 64 * w + 16 * n + lr;
        float bgv = bg[a_];
#pragma unroll
        for (int m = 0; m < 4; ++m) {
#pragma unroll
            for (int g2 = 0; g2 < 4; ++g2) {
                int t = 16 * m + 4 * lg + g2;
                float z  = Z[m][n][g2] + bgv;
                float e2 = __expf(2.0f * z);
                out[((size_t)(t0 + t) * BATCH + b) * ADIM + a_] = 1.0f - 2.0f / (e2 + 1.0f);
            }
        }
    }
}

// ================= fallback: validated round-6 single kernel =================
#define XJ_STRIDE 264
#define P_STRIDE  72
#define OFF_XJ  0
#define OFF_HT  33792
#define OFF_P   66560
#define OFF_SQT 75776
#define OFF_SQJ 76032
#define LDS_BYTES 76288

static __device__ __forceinline__ void stage64(const float* __restrict__ src, int row0, int b,
                                               unsigned short* dst, float* sqout, int tid)
{
#pragma unroll
    for (int r = 0; r < 8; ++r) {
        int idx = tid + NTH * r;
        int row = idx >> 5, e8 = idx & 31;
        const float* p = src + ((size_t)(row0 + row) * BATCH + b) * EDIM + e8 * 8;
        float4 v0 = *(const float4*)p;
        float4 v1 = *(const float4*)(p + 4);
        float vv[8] = {v0.x, v0.y, v0.z, v0.w, v1.x, v1.y, v1.z, v1.w};
        short8 pk;
        float s = 0.f;
#pragma unroll
        for (int e = 0; e < 8; ++e) {
            unsigned short us = f2bf(vv[e]);
            pk[e] = (short)us;
            float hf = bf2f(us);
            s += hf * hf;
        }
        *(short8*)(dst + row * XJ_STRIDE + e8 * 8) = pk;
        s += __shfl_xor(s, 1);
        s += __shfl_xor(s, 2);
        s += __shfl_xor(s, 4);
        s += __shfl_xor(s, 8);
        s += __shfl_xor(s, 16);
        if ((tid & 31) == 0) sqout[row] = s;
    }
}

static __device__ __forceinline__ void stage64_split(const float* __restrict__ src, int row0, int b,
                                                     unsigned short* dhi, unsigned short* dlo, int tid)
{
#pragma unroll
    for (int r = 0; r < 8; ++r) {
        int idx = tid + NTH * r;
        int row = idx >> 5, e8 = idx & 31;
        const float* p = src + ((size_t)(row0 + row) * BATCH + b) * HDIM + e8 * 8;
        float4 v0 = *(const float4*)p;
        float4 v1 = *(const float4*)(p + 4);
        float vv[8] = {v0.x, v0.y, v0.z, v0.w, v1.x, v1.y, v1.z, v1.w};
        short8 ph, plo;
#pragma unroll
        for (int e = 0; e < 8; ++e) {
            unsigned short hi = f2bf(vv[e]);
            ph[e] = (short)hi;
            plo[e] = (short)f2bf(vv[e] - bf2f(hi));
        }
        *(short8*)(dhi + row * XJ_STRIDE + e8 * 8) = ph;
        *(short8*)(dlo + row * XJ_STRIDE + e8 * 8) = plo;
    }
}

__global__ __launch_bounds__(NTH, 2)
void fused_mfma(const float* __restrict__ x, const float* __restrict__ h,
                const float* __restrict__ wsim, const float* __restrict__ bsim,
                const float* __restrict__ Wg, const float* __restrict__ bg,
                float* __restrict__ out)
{
    extern __shared__ char smem[];
    unsigned short* xjb    = (unsigned short*)(smem + OFF_XJ);
    char*           htb    = smem + OFF_HT;
    unsigned short* Pl     = (unsigned short*)(smem + OFF_P);
    float*          sqt_l  = (float*)(smem + OFF_SQT);
    float*          sqj_l  = (float*)(smem + OFF_SQJ);
    unsigned short* cat_hi = xjb;
    unsigned short* cat_lo = (unsigned short*)(smem + OFF_HT);

    const int tid  = threadIdx.x;
    const int lane = tid & 63;
    const int w    = tid >> 6;
    const int lr   = lane & 15;
    const int lg   = lane >> 4;

    const int lin = blockIdx.x;
    const int xcd = lin & 7;
    const int kk  = lin >> 3;
    const int b   = (kk >> 4) * 8 + xcd;
    const int t0  = (kk & 15) * 64;

    const float w_s = wsim[0];
    const float b_s = bsim[0];

    stage64(x, t0, b, xjb, sqt_l, tid);
    __syncthreads();
    short8 at[8];
#pragma unroll
    for (int kc = 0; kc < 8; ++kc)
        at[kc] = *(short8*)(xjb + (16 * w + lr) * XJ_STRIDE + kc * 32 + lg * 8);
    float sqt_reg[4];
#pragma unroll
    for (int g2 = 0; g2 < 4; ++g2) sqt_reg[g2] = sqt_l[16 * w + 4 * lg + g2];
    __syncthreads();

    float rsum[4] = {0.f, 0.f, 0.f, 0.f};
    f32x4 Gacc[16];
#pragma unroll
    for (int n = 0; n < 16; ++n) Gacc[n] = (f32x4){0.f, 0.f, 0.f, 0.f};

    const size_t jstride = (size_t)BATCH * HDIM;

    for (int jt = 0; jt < 16; ++jt) {
        const int j0 = jt * 64;
        stage64(x, j0, b, xjb, sqj_l, tid);
        {
            const float* hp = h + (size_t)j0 * jstride + (size_t)b * HDIM + tid;
#pragma unroll
            for (int q = 0; q < 8; ++q) {
                const float* pq = hp + (size_t)(8 * q) * jstride;
                unsigned int d0 = (unsigned int)f2bf(pq[0])           | ((unsigned int)f2bf(pq[jstride]) << 16);
                unsigned int d1 = (unsigned int)f2bf(pq[2 * jstride]) | ((unsigned int)f2bf(pq[3 * jstride]) << 16);
                unsigned int d2 = (unsigned int)f2bf(pq[4 * jstride]) | ((unsigned int)f2bf(pq[5 * jstride]) << 16);
                unsigned int d3 = (unsigned int)f2bf(pq[6 * jstride]) | ((unsigned int)f2bf(pq[7 * jstride]) << 16);
                *(u32x4*)(htb + tid * 128 + 16 * (q ^ (tid & 7))) = (u32x4){d0, d1, d2, d3};
            }
        }
        __syncthreads();

        f32x4 acc[4];
#pragma unroll
        for (int n = 0; n < 4; ++n) {
            acc[n] = (f32x4){0.f, 0.f, 0.f, 0.f};
#pragma unroll
            for (int kc = 0; kc < 8; ++kc) {
                short8 bf = *(short8*)(xjb + (16 * n + lr) * XJ_STRIDE + kc * 32 + lg * 8);
                acc[n] = __builtin_amdgcn_mfma_f32_16x16x32_bf16(at[kc], bf, acc[n], 0, 0, 0);
            }
        }

        float sqjv[4];
#pragma unroll
        for (int n = 0; n < 4; ++n) sqjv[n] = sqj_l[16 * n + lr];
#pragma unroll
        for (int n = 0; n < 4; ++n) {
#pragma unroll
            for (int g2 = 0; g2 < 4; ++g2) {
                float d2v  = sqt_reg[g2] + sqjv[n] - 2.0f * acc[n][g2];
                float dist = sqrtf(fmaxf(d2v, 0.0f) + 1e-12f);
                float pv   = __expf(fmaf(w_s, dist, b_s));
                rsum[g2] += pv;
                Pl[(16 * w + 4 * lg + g2) * P_STRIDE + 16 * n + lr] = f2bf(pv);
            }
        }

        short8 pa0 = *(short8*)(Pl + (16 * w + lr) * P_STRIDE + lg * 8);
        short8 pa1 = *(short8*)(Pl + (16 * w + lr) * P_STRIDE + 32 + lg * 8);
#pragma unroll
        for (int n = 0; n < 16; ++n) {
            int c = 16 * n + lr;
            short8 b0 = *(short8*)(htb + c * 128 + 16 * (lg ^ (c & 7)));
            short8 b1 = *(short8*)(htb + c * 128 + 16 * ((4 + lg) ^ (c & 7)));
            Gacc[n] = __builtin_amdgcn_mfma_f32_16x16x32_bf16(pa0, b0, Gacc[n], 0, 0, 0);
            Gacc[n] = __builtin_amdgcn_mfma_f32_16x16x32_bf16(pa1, b1, Gacc[n], 0, 0, 0);
        }
        __syncthreads();
    }

    float inv[4];
#pragma unroll
    for (int g2 = 0; g2 < 4; ++g2) {
        float s = rsum[g2];
        s += __shfl_xor(s, 1);
        s += __shfl_xor(s, 2);
        s += __shfl_xor(s, 4);
        s += __shfl_xor(s, 8);
        inv[g2] = 1.0f / s;
    }

#pragma unroll
    for (int n = 0; n < 16; ++n) {
#pragma unroll
        for (int g2 = 0; g2 < 4; ++g2) {
            float gn = Gacc[n][g2] * inv[g2];
            unsigned short hi = f2bf(gn);
            unsigned short lo = f2bf(gn - bf2f(hi));
            int t = 16 * w + 4 * lg + g2;
            int c = 16 * n + lr;
            cat_hi[t * XJ_STRIDE + c] = hi;
            cat_lo[t * XJ_STRIDE + c] = lo;
        }
    }
    __syncthreads();

    f32x4 Z[4][4];
#pragma unroll
    for (int m = 0; m < 4; ++m)
#pragma unroll
        for (int n = 0; n < 4; ++n) Z[m][n] = (f32x4){0.f, 0.f, 0.f, 0.f};

    for (int half = 0; half < 2; ++half) {
        if (half == 1) {
            __syncthreads();
            stage64_split(h, t0, b, cat_hi, cat_lo, tid);
            __syncthreads();
        }
#pragma unroll
        for (int kc = 0; kc < 8; ++kc) {
            short8 ah[4], al[4];
#pragma unroll
            for (int m = 0; m < 4; ++m) {
                ah[m] = *(short8*)(cat_hi + (16 * m + lr) * XJ_STRIDE + kc * 32 + lg * 8);
                al[m] = *(short8*)(cat_lo + (16 * m + lr) * XJ_STRIDE + kc * 32 + lg * 8);
            }
#pragma unroll
            for (int n = 0; n < 4; ++n) {
                int a_ = 64 * w + 16 * n + lr;
                const float* wp = Wg + (size_t)a_ * (2 * HDIM) + half * HDIM + kc * 32 + lg * 8;
                float4 wv0 = *(const float4*)wp;
                float4 wv1 = *(const float4*)(wp + 4);
                float vv[8] = {wv0.x, wv0.y, wv0.z, wv0.w, wv1.x, wv1.y, wv1.z, wv1.w};
                short8 bh, bl;
#pragma unroll
                for (int e = 0; e < 8; ++e) {
                    unsigned short hi = f2bf(vv[e]);
                    bh[e] = (short)hi;
                    bl[e] = (short)f2bf(vv[e] - bf2f(hi));
                }
#pragma unroll
                for (int m = 0; m < 4; ++m) {
                    Z[m][n] = __builtin_amdgcn_mfma_f32_16x16x32_bf16(ah[m], bh, Z[m][n], 0, 0, 0);
                    Z[m][n] = __builtin_amdgcn_mfma_f32_16x16x32_bf16(al[m], bh, Z[m][n], 0, 0, 0);
                    Z[m][n] = __builtin_amdgcn_mfma_f32_16x16x32_bf16(ah[m], bl, Z[m][n], 0, 0, 0);
                }
            }
        }
    }

#pragma unroll
    for (int n = 0; n < 4; ++n) {
        int a_ = 64 * w + 16 * n + lr;
        float bgv = bg[a_];
#pragma unroll
        for (int m = 0; m < 4; ++m) {
#pragma unroll
            for (int g2 = 0; g2 < 4; ++g2) {
                int t = 16 * m + 4 * lg + g2;
                float z  = Z[m][n][g2] + bgv;
                float e2 = __expf(2.0f * z);
                out[((size_t)(t0 + t) * BATCH + b) * ADIM + a_] = 1.0f - 2.0f / (e2 + 1.0f);
            }
        }
    }
}

extern "C" void kernel_launch(void* const* d_in, const int* in_sizes, int n_in,
                              void* d_out, int out_size, void* d_ws, size_t ws_size,
                              hipStream_t stream) {
    const float* x    = (const float*)d_in[0];
    const float* h    = (const float*)d_in[1];
    const float* wsim = (const float*)d_in[2];
    const float* bsim = (const float*)d_in[3];
    const float* Wg   = (const float*)d_in[4];
    const float* bg   = (const float*)d_in[5];
    float* out = (float*)d_out;

    if (ws_size >= (size_t)WS_NEED && d_ws != nullptr) {
        char* ws = (char*)d_ws;
        unsigned short* xbf  = (unsigned short*)(ws + XBF_OFF);
        unsigned short* hTg  = (unsigned short*)(ws + HT_OFF);
        unsigned short* hhi  = (unsigned short*)(ws + HHI_OFF);
        unsigned short* hlo  = (unsigned short*)(ws + HLO_OFF);
        unsigned short* wghi = (unsigned short*)(ws + WGHI_OFF);
        unsigned short* wglo = (unsigned short*)(ws + WGLO_OFF);
        float*          sqx  = (float*)(ws + SQX_OFF);

        hipLaunchKernelGGL(pre_convert, dim3(8192), dim3(NTH), 0, stream, x, h, xbf, hhi, hlo, sqx);
        hipLaunchKernelGGL(pre_ht,      dim3(2048), dim3(NTH), 0, stream, h, hTg);
        hipLaunchKernelGGL(pre_wg,      dim3(64),   dim3(NTH), 0, stream, Wg, wghi, wglo);

        (void)hipFuncSetAttribute((const void*)fused2,
                                  hipFuncAttributeMaxDynamicSharedMemorySize, LDS2_BYTES);
        hipLaunchKernelGGL(fused2, dim3(512), dim3(NTH), LDS2_BYTES, stream,
                           xbf, hTg, hhi, hlo, wghi, wglo, sqx, wsim, bsim, bg, out);
    } else {
        (void)hipFuncSetAttribute((const void*)fused_mfma,
                                  hipFuncAttributeMaxDynamicSharedMemorySize, LDS_BYTES);
        hipLaunchKernelGGL(fused_mfma, dim3(512), dim3(NTH), LDS_BYTES, stream,
                           x, h, wsim, bsim, Wg, bg, out);
    }
}